// Round 8
// baseline (8904.997 us; speedup 1.0000x reference)
//
#include <hip/hip_runtime.h>

// DeepRLSNet: batched RLS. B=64, N=T=2000, TAPS=64.
// Per step:
//   lam = clip(lambdas[t], 1e-4, 0.9999)
//   Px = P@x ; den = lam + x.Px ; g = Px/den ; y = w.x
//   w += g*(d-y) ; P = (P - outer(g, x@P))/lam   (honest x@P — R2 post-mortem)
//
// R8 = R7 pipeline + 4 batches per block (TLP fix).
// R5-R7 showed the kernel is stall-bound at 1 wave/SIMD: dependent VALU
// latency + LDS/barrier latency fully exposed, work changes move time ~6%.
// Packing 4 independent batch-slices (256 threads each) into one 1024-thread
// block gives 4 waves/SIMD whose stalls mutually fill. Slices run identical
// instruction streams -> barrier skew minimal; per-batch math is bitwise
// identical to R7 (absmax should reproduce exactly).
//
// Within a slice: thread t=r*4+q owns 16-wide quarter-rows of Q and QT(=Q^T);
// sigma-scaling (P = sigma*Q, sigma *= 1/lam); DPP quad_perm reduces;
// rcp+Newton reciprocals; raw lgkmcnt-only barrier (global prefetch rides).

#define B_ 64
#define N_ 2000
#define TAPS_ 64
#define T_ 2000
#define STEPS_ 2000   // divisible by 4
#define BPB_ 4        // batches per block

__device__ __forceinline__ void lds_barrier() {
    // LDS-only fence + barrier: global (vmcnt) prefetch stays in flight.
    asm volatile("s_waitcnt lgkmcnt(0)\n\ts_barrier" ::: "memory");
}

__device__ __forceinline__ float clipl(float v) {
    return fminf(fmaxf(v, 1e-4f), 0.9999f);
}

// sum over the 4 q-lanes of a quad via DPP quad_perm (VALU-latency class).
__device__ __forceinline__ float quad_reduce(float v) {
    int t1 = __builtin_amdgcn_update_dpp(__float_as_int(v), __float_as_int(v),
                                         0xB1, 0xF, 0xF, false);   // xor 1
    v += __int_as_float(t1);
    int t2 = __builtin_amdgcn_update_dpp(__float_as_int(v), __float_as_int(v),
                                         0x4E, 0xF, 0xF, false);   // xor 2
    v += __int_as_float(t2);
    return v;   // bitwise-identical in all 4 lanes of the quad
}

// 1/v via v_rcp_f32 + one Newton step (~0.5 ulp).
__device__ __forceinline__ float rcp_nr(float v) {
    float r = __builtin_amdgcn_rcpf(v);
    float e = fmaf(-v, r, 1.0f);
    return fmaf(r, e, r);
}

__global__ __launch_bounds__(256 * BPB_, 1) void rls_kernel(
    const float* __restrict__ x_seq,   // [B, N, TAPS]
    const float* __restrict__ d_seq,   // [B, N]
    const float* __restrict__ lambdas, // [T]
    float* __restrict__ y_out,         // [B, N]
    float* __restrict__ w_out)         // [B, TAPS]
{
    const int sub = threadIdx.x >> 8;        // batch slice 0..3
    const int tid = threadIdx.x & 255;       // within-slice tid
    const int b   = blockIdx.x * BPB_ + sub; // global batch
    const int r   = tid >> 2;    // row 0..63
    const int q   = tid & 3;     // quarter 0..3
    const int qb  = q << 4;

    __shared__ __align__(16) float qxs[BPB_][2][TAPS_];  // Qx broadcast (dbuf)
    __shared__ __align__(16) float xqs[BPB_][2][TAPS_];  // xQ broadcast (dbuf)
    __shared__ __align__(16) float d_lds[BPB_][STEPS_];
    __shared__ __align__(16) float lam_lds[STEPS_];

    const float* xb = x_seq + (size_t)b * N_ * TAPS_;
    const float* db = d_seq + (size_t)b * N_;

    for (int idx = tid; idx < STEPS_; idx += 256) {
        d_lds[sub][idx] = db[idx];
        if (sub == 0) lam_lds[idx] = lambdas[idx];
    }

    auto loadx = [&](float (&dst)[16], int t) {
        const float4* xv = (const float4*)(xb + (size_t)t * TAPS_ + qb);
        #pragma unroll
        for (int j4 = 0; j4 < 4; ++j4) {
            float4 v = xv[j4];
            dst[j4*4+0]=v.x; dst[j4*4+1]=v.y; dst[j4*4+2]=v.z; dst[j4*4+3]=v.w;
        }
    };

    float Q[16], QT[16], w[16];
    #pragma unroll
    for (int j = 0; j < 16; ++j) {
        const float id = (qb + j == r) ? 1.0f : 0.0f;
        Q[j] = id; QT[j] = id; w[j] = 0.0f;
    }
    float sigma = 1.0f;   // P = sigma * Q

    float xA[16], xB[16], xC[16], xD[16];
    loadx(xA, 0);
    loadx(xB, 1);

    lds_barrier();   // d_lds / lam_lds visible

    auto body = [&](int step, float (&x)[16], float (&xn)[16]) {
        const float d_t   = d_lds[sub][step];
        const float lam_t = lam_lds[step];

        // ---- pre-barrier: quarter partials of Qx[r], xQ[r], w.x ----
        float qxr = 0.f, xqr = 0.f, py = 0.f;
        #pragma unroll
        for (int j = 0; j < 16; ++j) {
            qxr = fmaf(Q[j],  x[j], qxr);
            xqr = fmaf(QT[j], x[j], xqr);
            py  = fmaf(w[j],  x[j], py);
        }
        qxr = quad_reduce(qxr);
        xqr = quad_reduce(xqr);
        py  = quad_reduce(py);

        float* pb = qxs[sub][step & 1];
        float* qp = xqs[sub][step & 1];
        if (q == 0) { pb[r] = qxr; qp[r] = xqr; }
        lds_barrier();

        // ---- distance-2 x prefetch (rides across raw barriers) ----
        const int tn = (step + 2 < STEPS_) ? (step + 2) : (STEPS_ - 1);
        loadx(xn, tn);

        // ---- read back quarters of Qx and xQ ----
        float Qxq[16], xQq[16];
        {
            const float4* pv = (const float4*)(pb + qb);
            const float4* qv = (const float4*)(qp + qb);
            #pragma unroll
            for (int j4 = 0; j4 < 4; ++j4) {
                float4 a4 = pv[j4], c4 = qv[j4];
                Qxq[j4*4+0]=a4.x; Qxq[j4*4+1]=a4.y; Qxq[j4*4+2]=a4.z; Qxq[j4*4+3]=a4.w;
                xQq[j4*4+0]=c4.x; xQq[j4*4+1]=c4.y; xQq[j4*4+2]=c4.z; xQq[j4*4+3]=c4.w;
            }
        }

        // ---- den = clip(lam) + sigma * (x . Qx) ----
        float p0=0.f,p1=0.f,p2=0.f,p3=0.f;
        #pragma unroll
        for (int j = 0; j < 16; j += 4) {
            p0 = fmaf(x[j+0], Qxq[j+0], p0);
            p1 = fmaf(x[j+1], Qxq[j+1], p1);
            p2 = fmaf(x[j+2], Qxq[j+2], p2);
            p3 = fmaf(x[j+3], Qxq[j+3], p3);
        }
        float pd = quad_reduce((p0+p1)+(p2+p3));

        const float lamc    = clipl(lam_t);
        const float den     = fmaf(sigma, pd, lamc);
        const float inv_den = rcp_nr(den);
        const float inv_lam = rcp_nr(lamc);
        const float s       = sigma * inv_den;   // g = s * Qx
        const float err     = d_t - py;
        const float es      = s * err;

        if (tid == 0) y_out[(size_t)b * N_ + step] = py;

        // ---- t[j] = s*Qx[j] (bitwise-uniform across owners/readers) ----
        float tq[16];
        #pragma unroll
        for (int j = 0; j < 16; ++j) tq[j] = s * Qxq[j];
        const float tr = s * qxr;   // == tq value others hold for row r

        // ---- w += g*err = Qx * es ----
        #pragma unroll
        for (int j = 0; j < 16; ++j) w[j] = fmaf(Qxq[j], es, w[j]);

        // ---- Q[r][c]  -= t_r * xQ[c]   (no /lam: folded into sigma) ----
        #pragma unroll
        for (int j = 0; j < 16; ++j) Q[j]  = fmaf(-tr, xQq[j], Q[j]);
        // ---- QT[r][c] = Q[c][r] -= t_c * xQ[r] ----
        #pragma unroll
        for (int j = 0; j < 16; ++j) QT[j] = fmaf(-tq[j], xqr, QT[j]);

        sigma *= inv_lam;   // P_{t+1} = sigma_{t+1} * Q_{t+1}
    };

    for (int t = 0; t < STEPS_; t += 4) {
        body(t + 0, xA, xC);
        body(t + 1, xB, xD);
        body(t + 2, xC, xA);
        body(t + 3, xD, xB);
    }

    // ---- final weights: row-group 0 holds a full replica across q ----
    if (r == 0) {
        float4* wo = (float4*)(w_out + (size_t)b * TAPS_ + qb);
        #pragma unroll
        for (int j4 = 0; j4 < 4; ++j4)
            wo[j4] = make_float4(w[j4*4+0], w[j4*4+1], w[j4*4+2], w[j4*4+3]);
    }
}

extern "C" void kernel_launch(void* const* d_in, const int* in_sizes, int n_in,
                              void* d_out, int out_size, void* d_ws, size_t ws_size,
                              hipStream_t stream) {
    const float* x_seq   = (const float*)d_in[0];
    const float* d_seq   = (const float*)d_in[1];
    const float* lambdas = (const float*)d_in[2];

    float* y_out = (float*)d_out;                      // B*N floats
    float* w_out = (float*)d_out + (size_t)B_ * N_;    // B*TAPS floats

    rls_kernel<<<B_ / BPB_, 256 * BPB_, 0, stream>>>(x_seq, d_seq, lambdas,
                                                     y_out, w_out);
}

// Round 9
// 1049.600 us; speedup vs baseline: 8.4842x; 8.4842x over previous
//
#include <hip/hip_runtime.h>

// DeepRLSNet: batched RLS. B=64, N=T=2000, TAPS=64.
// Per step:
//   lam = clip(lambdas[t], 1e-4, 0.9999)
//   Px = P@x ; den = lam + x.Px ; g = Px/den ; y = w.x
//   w += g*(d-y) ; P = (P - outer(g, x@P))/lam   (honest x@P — R2 post-mortem)
//
// R9 = R7 pipeline, but TWO steps per barrier round (chain surgery).
// R8 lesson: extra waves can't shorten the per-step critical path (and
// 1024-thread launch_bounds forced a 64-VGPR spill disaster). The path is
// dominated by the LDS round-trip + barrier, so do one round per 2 steps
// via exact Sherman-Morrison identities in sigma-space (P = sigma*Q):
//   u = Q x1, v = Q^T x1, a = xQ.x1, b = Qx.x1, c2 = x1.u
//   Qx1 = u - (s0*a)*Qx ; xQ1 = v - (s0*b)*xQ ; pd1 = c2 - (s0*a)*b
//   y1  = w.x1 + es0*b   (w-update folded analytically)
//   Q_{t+2} = Q - s0*outer(Qx,xQ) - s1*outer(Qx1,xQ1)  (both honest terms)
// QT stays bitwise == Q^T: both update terms use identical fused products
// built from bitwise-uniform broadcast/derived values on both sides.
// 64 blocks x 256 threads; thread t=r*4+q owns 16-wide quarter-rows.

#define B_ 64
#define N_ 2000
#define TAPS_ 64
#define T_ 2000
#define STEPS_ 2000   // divisible by 4 (2 rounds per unrolled iter)

__device__ __forceinline__ void lds_barrier() {
    // LDS-only fence + barrier: global (vmcnt) prefetch stays in flight.
    asm volatile("s_waitcnt lgkmcnt(0)\n\ts_barrier" ::: "memory");
}

__device__ __forceinline__ float clipl(float v) {
    return fminf(fmaxf(v, 1e-4f), 0.9999f);
}

// sum over the 4 q-lanes of a quad via DPP quad_perm (VALU-latency class).
__device__ __forceinline__ float quad_reduce(float v) {
    int t1 = __builtin_amdgcn_update_dpp(__float_as_int(v), __float_as_int(v),
                                         0xB1, 0xF, 0xF, false);   // xor 1
    v += __int_as_float(t1);
    int t2 = __builtin_amdgcn_update_dpp(__float_as_int(v), __float_as_int(v),
                                         0x4E, 0xF, 0xF, false);   // xor 2
    v += __int_as_float(t2);
    return v;   // bitwise-identical in all 4 lanes of the quad
}

// 1/v via v_rcp_f32 + one Newton step (~0.5 ulp).
__device__ __forceinline__ float rcp_nr(float v) {
    float r = __builtin_amdgcn_rcpf(v);
    float e = fmaf(-v, r, 1.0f);
    return fmaf(r, e, r);
}

__global__ __launch_bounds__(256, 1) void rls_kernel(
    const float* __restrict__ x_seq,   // [B, N, TAPS]
    const float* __restrict__ d_seq,   // [B, N]
    const float* __restrict__ lambdas, // [T]
    float* __restrict__ y_out,         // [B, N]
    float* __restrict__ w_out)         // [B, TAPS]
{
    const int b   = blockIdx.x;
    const int tid = threadIdx.x;
    const int r   = tid >> 2;    // row 0..63
    const int q   = tid & 3;     // quarter 0..3
    const int qb  = q << 4;

    // broadcast buffers: [parity][vec][64], vec: 0=Qx 1=xQ 2=u 3=v
    __shared__ __align__(16) float bufs[2][4][TAPS_];
    __shared__ __align__(16) float d_lds[STEPS_];
    __shared__ __align__(16) float lam_lds[STEPS_];

    const float* xb = x_seq + (size_t)b * N_ * TAPS_;
    const float* db = d_seq + (size_t)b * N_;

    for (int idx = tid; idx < STEPS_; idx += 256) {
        d_lds[idx]   = db[idx];
        lam_lds[idx] = lambdas[idx];
    }

    auto loadx = [&](float (&dst)[16], int t) {
        const float4* xv = (const float4*)(xb + (size_t)t * TAPS_ + qb);
        #pragma unroll
        for (int j4 = 0; j4 < 4; ++j4) {
            float4 v = xv[j4];
            dst[j4*4+0]=v.x; dst[j4*4+1]=v.y; dst[j4*4+2]=v.z; dst[j4*4+3]=v.w;
        }
    };

    float Q[16], QT[16], w[16];
    #pragma unroll
    for (int j = 0; j < 16; ++j) {
        const float id = (qb + j == r) ? 1.0f : 0.0f;
        Q[j] = id; QT[j] = id; w[j] = 0.0f;
    }
    float sig = 1.0f;   // P = sig * Q

    float xA[16], xB[16], xC[16], xD[16];
    loadx(xA, 0);
    loadx(xB, 1);

    lds_barrier();   // d_lds / lam_lds visible

    // one round = steps t, t+1. x0=x_t, x1=x_{t+1}; prefetch x_{t+2},x_{t+3}.
    auto round = [&](int t, float (&x0)[16], float (&x1)[16],
                     float (&xp0)[16], float (&xp1)[16], int par) {
        const float d0   = d_lds[t];
        const float d1   = d_lds[t + 1];
        const float lam0 = clipl(lam_lds[t]);
        const float lam1 = clipl(lam_lds[t + 1]);
        const float il0  = rcp_nr(lam0);
        const float il1  = rcp_nr(lam1);

        // ---- pre-barrier: 6 quarter-dots ----
        float qxr = 0.f, xqr = 0.f, ur = 0.f, vr = 0.f, wy0 = 0.f, wy1 = 0.f;
        #pragma unroll
        for (int j = 0; j < 16; ++j) {
            qxr = fmaf(Q[j],  x0[j], qxr);
            xqr = fmaf(QT[j], x0[j], xqr);
            ur  = fmaf(Q[j],  x1[j], ur);
            vr  = fmaf(QT[j], x1[j], vr);
            wy0 = fmaf(w[j],  x0[j], wy0);
            wy1 = fmaf(w[j],  x1[j], wy1);
        }
        qxr = quad_reduce(qxr);  xqr = quad_reduce(xqr);
        ur  = quad_reduce(ur);   vr  = quad_reduce(vr);
        wy0 = quad_reduce(wy0);  wy1 = quad_reduce(wy1);

        // lane q of each quad writes vector q (values replicated in quad)
        {
            float val = (q == 0) ? qxr : (q == 1) ? xqr : (q == 2) ? ur : vr;
            bufs[par][q][r] = val;
        }
        lds_barrier();

        // ---- prefetch next round's x (rides across raw barriers) ----
        const int tp0 = (t + 2 < STEPS_) ? (t + 2) : (STEPS_ - 1);
        const int tp1 = (t + 3 < STEPS_) ? (t + 3) : (STEPS_ - 1);
        loadx(xp0, tp0);
        loadx(xp1, tp1);

        // ---- read back quarters of Qx, xQ, u, v ----
        float Qxq[16], xQq[16], uq[16], vq[16];
        {
            const float4* p0 = (const float4*)(&bufs[par][0][qb]);
            const float4* p1 = (const float4*)(&bufs[par][1][qb]);
            const float4* p2 = (const float4*)(&bufs[par][2][qb]);
            const float4* p3 = (const float4*)(&bufs[par][3][qb]);
            #pragma unroll
            for (int j4 = 0; j4 < 4; ++j4) {
                float4 a4 = p0[j4], b4 = p1[j4], c4 = p2[j4], e4 = p3[j4];
                Qxq[j4*4+0]=a4.x; Qxq[j4*4+1]=a4.y; Qxq[j4*4+2]=a4.z; Qxq[j4*4+3]=a4.w;
                xQq[j4*4+0]=b4.x; xQq[j4*4+1]=b4.y; xQq[j4*4+2]=b4.z; xQq[j4*4+3]=b4.w;
                uq [j4*4+0]=c4.x; uq [j4*4+1]=c4.y; uq [j4*4+2]=c4.z; uq [j4*4+3]=c4.w;
                vq [j4*4+0]=e4.x; vq [j4*4+1]=e4.y; vq [j4*4+2]=e4.z; vq [j4*4+3]=e4.w;
            }
        }

        // ---- 4 post-barrier quarter-dots: pd0, a, b, c2 ----
        float pd0=0.f, a=0.f, bb=0.f, c2=0.f;
        #pragma unroll
        for (int j = 0; j < 16; ++j) {
            pd0 = fmaf(x0[j], Qxq[j], pd0);
            a   = fmaf(x1[j], xQq[j], a);
            bb  = fmaf(x1[j], Qxq[j], bb);
            c2  = fmaf(x1[j], uq[j],  c2);
        }
        pd0 = quad_reduce(pd0);  a  = quad_reduce(a);
        bb  = quad_reduce(bb);   c2 = quad_reduce(c2);

        // ---- step t scalars ----
        const float den0 = fmaf(sig, pd0, lam0);
        const float s0   = sig * rcp_nr(den0);
        const float err0 = d0 - wy0;
        const float es0  = s0 * err0;
        const float sa   = s0 * a;
        const float sb   = s0 * bb;

        // ---- step t+1 scalars (in-register Sherman-Morrison) ----
        const float sig1 = sig * il0;
        const float pd1  = fmaf(-sa, bb, c2);
        const float den1 = fmaf(sig1, pd1, lam1);
        const float s1   = sig1 * rcp_nr(den1);
        const float y1   = fmaf(es0, bb, wy1);
        const float err1 = d1 - y1;
        const float es1  = s1 * err1;
        sig = sig1 * il1;

        if (tid == 0)
            *(float2*)(y_out + (size_t)b * N_ + t) = make_float2(wy0, y1);

        // ---- derived step-(t+1) vectors (bitwise-uniform both sides) ----
        const float qx1r = fmaf(-sa, qxr, ur);
        const float xq1r = fmaf(-sb, xqr, vr);
        const float tr0  = s0 * qxr;
        const float tr1  = s1 * qx1r;

        #pragma unroll
        for (int j = 0; j < 16; ++j) {
            const float Qx1  = fmaf(-sa, Qxq[j], uq[j]);   // Qx1[c]
            const float xQ1  = fmaf(-sb, xQq[j], vq[j]);   // xQ1[c]
            const float tq0  = s0 * Qxq[j];
            const float tq1  = s1 * Qx1;
            // w: two honest rank-1 adds
            w[j] = fmaf(Qxq[j], es0, w[j]);
            w[j] = fmaf(Qx1,    es1, w[j]);
            // Q row r: subtract both outer-product terms
            Q[j] = fmaf(-tr0, xQq[j], Q[j]);
            Q[j] = fmaf(-tr1, xQ1,    Q[j]);
            // QT row r (= Q column r): transposed products, identical bits
            QT[j] = fmaf(-tq0, xqr,  QT[j]);
            QT[j] = fmaf(-tq1, xq1r, QT[j]);
        }
    };

    for (int t = 0; t < STEPS_; t += 4) {
        round(t + 0, xA, xB, xC, xD, 0);
        round(t + 2, xC, xD, xA, xB, 1);
    }

    // ---- final weights: row-group 0 holds a full replica across q ----
    if (r == 0) {
        float4* wo = (float4*)(w_out + (size_t)b * TAPS_ + qb);
        #pragma unroll
        for (int j4 = 0; j4 < 4; ++j4)
            wo[j4] = make_float4(w[j4*4+0], w[j4*4+1], w[j4*4+2], w[j4*4+3]);
    }
}

extern "C" void kernel_launch(void* const* d_in, const int* in_sizes, int n_in,
                              void* d_out, int out_size, void* d_ws, size_t ws_size,
                              hipStream_t stream) {
    const float* x_seq   = (const float*)d_in[0];
    const float* d_seq   = (const float*)d_in[1];
    const float* lambdas = (const float*)d_in[2];

    float* y_out = (float*)d_out;                      // B*N floats
    float* w_out = (float*)d_out + (size_t)B_ * N_;    // B*TAPS floats

    rls_kernel<<<B_, 256, 0, stream>>>(x_seq, d_seq, lambdas, y_out, w_out);
}